// Round 1
// baseline (629.061 us; speedup 1.0000x reference)
//
#include <hip/hip_runtime.h>
#include <math.h>

// Problem: AdaptiveContrastiveLoss — x[4096][512] f32 -> scalar f32 loss.
// Pipeline: row-norms -> fp32 GEMM sim=Xn*Xn^T (64MB in ws) -> exact dual
// radix-select (two order statistics of flattened sim) -> masked-mean loss.
// ws layout: [0,64MB) sim | [64MB, +16KB) rinv | then Meta block.
// Assumes ws_size >= ~67.2 MB.

#define N 4096
#define D 512
#define NN 16777216u  // N*N

struct Meta {
  unsigned int hist[2][256];   // dual 256-bin histograms (radix select)
  unsigned int prefix[2];      // key prefix being built, [0]=neg, [1]=pos
  unsigned int rank[2];        // remaining rank within matching set
  unsigned int pcnt, ncnt, pad0, pad1;
  double psum, nsum;
};

// monotone float -> uint mapping (total order matching fp compare, NaN-free data)
__device__ __forceinline__ unsigned int f2key(float f) {
  unsigned int u = __float_as_uint(f);
  return (u & 0x80000000u) ? ~u : (u | 0x80000000u);
}
__device__ __forceinline__ float key2f(unsigned int k) {
  unsigned int u = (k & 0x80000000u) ? (k ^ 0x80000000u) : ~k;
  return __uint_as_float(u);
}

__global__ void init_meta(Meta* m, unsigned int kneg, unsigned int kpos) {
  // memsetAsync already zeroed everything else
  m->rank[0] = kneg;
  m->rank[1] = kpos;
}

// one block per row: rinv[row] = 1/max(||x_row||, 1e-8)
__global__ void row_norms(const float* __restrict__ x, float* __restrict__ rinv) {
  const int row = blockIdx.x;
  const int tid = threadIdx.x;                     // 256 threads, 2 floats each
  const float2 v = ((const float2*)(x + (size_t)row * D))[tid];
  float s = v.x * v.x + v.y * v.y;
#pragma unroll
  for (int o = 32; o > 0; o >>= 1) s += __shfl_xor(s, o);
  __shared__ float wsum[4];
  if ((tid & 63) == 0) wsum[tid >> 6] = s;
  __syncthreads();
  if (tid == 0) {
    float t = wsum[0] + wsum[1] + wsum[2] + wsum[3];
    rinv[row] = 1.0f / fmaxf(sqrtf(t), 1e-8f);
  }
}

// fp32 vector GEMM: sim[m][n] = sum_k (x[m][k]*rinv[m]) * (x[n][k]*rinv[n])
// 64x64 tile, 256 threads (16x16), 4x4 micro-tile, BK=16, k-major LDS tiles
// so fragment reads are contiguous float4 (ds_read_b128, conflict-free).
#define BM 64
#define BN 64
#define BK 16
__global__ __launch_bounds__(256) void gemm_sim(const float* __restrict__ x,
                                                const float* __restrict__ rinv,
                                                float* __restrict__ sim) {
  __shared__ float As[BK][BM];
  __shared__ float Bs[BK][BN];
  const int tid = threadIdx.x;
  const int tx = tid & 15, ty = tid >> 4;
  const int bm = blockIdx.x * BM;
  const int bn = blockIdx.y * BN;

  const int lrow = tid >> 2;          // 0..63
  const int lk4  = (tid & 3) * 4;     // 0,4,8,12
  const float scA = rinv[bm + lrow];
  const float scB = rinv[bn + lrow];
  const float* arow = x + (size_t)(bm + lrow) * D;
  const float* brow = x + (size_t)(bn + lrow) * D;

  float acc[4][4] = {};

  for (int k0 = 0; k0 < D; k0 += BK) {
    const float4 av = *(const float4*)(arow + k0 + lk4);
    const float4 bv = *(const float4*)(brow + k0 + lk4);
    __syncthreads();  // previous iteration's compute done before overwrite
    As[lk4 + 0][lrow] = av.x * scA;
    As[lk4 + 1][lrow] = av.y * scA;
    As[lk4 + 2][lrow] = av.z * scA;
    As[lk4 + 3][lrow] = av.w * scA;
    Bs[lk4 + 0][lrow] = bv.x * scB;
    Bs[lk4 + 1][lrow] = bv.y * scB;
    Bs[lk4 + 2][lrow] = bv.z * scB;
    Bs[lk4 + 3][lrow] = bv.w * scB;
    __syncthreads();
#pragma unroll
    for (int k = 0; k < BK; ++k) {
      float a[4], b[4];
      *(float4*)a = *(const float4*)&As[k][ty * 4];
      *(float4*)b = *(const float4*)&Bs[k][tx * 4];
#pragma unroll
      for (int i = 0; i < 4; ++i)
#pragma unroll
        for (int j = 0; j < 4; ++j) acc[i][j] += a[i] * b[j];
    }
  }
#pragma unroll
  for (int i = 0; i < 4; ++i) {
    float4 o = make_float4(acc[i][0], acc[i][1], acc[i][2], acc[i][3]);
    *(float4*)&sim[(size_t)(bm + ty * 4 + i) * N + bn + tx * 4] = o;
  }
}

// one 8-bit radix-select pass for BOTH order statistics.
// mask selects the already-fixed high bits; dup==1 (pass 0) => both
// selections share hist[0] (prefixes are identical there).
__global__ __launch_bounds__(256) void hist_pass(const float* __restrict__ sim,
                                                 Meta* __restrict__ m,
                                                 unsigned int shift,
                                                 unsigned int mask, int dup) {
  __shared__ unsigned int h[2][256];
  const int tid = threadIdx.x;
  h[0][tid] = 0;
  h[1][tid] = 0;
  __syncthreads();
  const unsigned int p0 = m->prefix[0];
  const unsigned int p1 = m->prefix[1];
  const size_t stride = (size_t)gridDim.x * blockDim.x;
  for (size_t i = (size_t)blockIdx.x * blockDim.x + tid; i < NN / 4; i += stride) {
    const float4 v = ((const float4*)sim)[i];
    const float f[4] = {v.x, v.y, v.z, v.w};
#pragma unroll
    for (int e = 0; e < 4; ++e) {
      const unsigned int key = f2key(f[e]);
      const unsigned int b = (key >> shift) & 255u;
      if (((key ^ p0) & mask) == 0) atomicAdd(&h[0][b], 1u);
      if (!dup && ((key ^ p1) & mask) == 0) atomicAdd(&h[1][b], 1u);
    }
  }
  __syncthreads();
  atomicAdd(&m->hist[0][tid], h[0][tid]);
  if (!dup) atomicAdd(&m->hist[1][tid], h[1][tid]);
}

// single small block: walk both histograms, pick digit, update prefix/rank,
// zero histograms for the next pass.
__global__ void scan_pass(Meta* m, unsigned int shift, int dup) {
  const int tid = threadIdx.x;  // 64 threads
  if (tid < 2) {
    const int hs = dup ? 0 : tid;
    unsigned int r = m->rank[tid];
    unsigned int cum = 0;
    unsigned int d = 0;
    for (d = 0; d < 256; ++d) {
      const unsigned int c = m->hist[hs][d];
      if (cum + c > r) break;
      cum += c;
    }
    if (d == 256) d = 255;  // safety (shouldn't happen)
    m->prefix[tid] |= d << shift;
    m->rank[tid] = r - cum;
  }
  __syncthreads();
  for (int i = tid; i < 512; i += blockDim.x) ((unsigned int*)m->hist)[i] = 0;
}

__global__ __launch_bounds__(256) void loss_pass(const float* __restrict__ sim,
                                                 Meta* __restrict__ m) {
  const float negT = key2f(m->prefix[0]);
  const float posT = key2f(m->prefix[1]);
  float ps = 0.f, ns = 0.f;
  unsigned int pc = 0, nc = 0;
  const int tid = threadIdx.x;
  const size_t stride = (size_t)gridDim.x * blockDim.x;
  for (size_t i = (size_t)blockIdx.x * blockDim.x + tid; i < NN / 4; i += stride) {
    const float4 v = ((const float4*)sim)[i];
    const float f[4] = {v.x, v.y, v.z, v.w};
#pragma unroll
    for (int e = 0; e < 4; ++e) {
      const float s = f[e];
      if (s > posT) { ps += fmaxf(1.0f - s, 0.0f); pc++; }
      if (s < negT) { ns += fmaxf(s, 0.0f); nc++; }
    }
  }
#pragma unroll
  for (int o = 32; o > 0; o >>= 1) {
    ps += __shfl_xor(ps, o);
    ns += __shfl_xor(ns, o);
    pc += __shfl_xor(pc, o);
    nc += __shfl_xor(nc, o);
  }
  __shared__ float sps[4], sns[4];
  __shared__ unsigned int spc[4], snc[4];
  if ((tid & 63) == 0) {
    const int w = tid >> 6;
    sps[w] = ps; sns[w] = ns; spc[w] = pc; snc[w] = nc;
  }
  __syncthreads();
  if (tid == 0) {
    atomicAdd(&m->psum, (double)(sps[0] + sps[1] + sps[2] + sps[3]));
    atomicAdd(&m->nsum, (double)(sns[0] + sns[1] + sns[2] + sns[3]));
    atomicAdd(&m->pcnt, spc[0] + spc[1] + spc[2] + spc[3]);
    atomicAdd(&m->ncnt, snc[0] + snc[1] + snc[2] + snc[3]);
  }
}

__global__ void finalize(const Meta* __restrict__ m, float* __restrict__ out) {
  const double pl = m->psum / (double)m->pcnt;
  const double nl = m->nsum / (double)m->ncnt;
  out[0] = (float)(pl + nl);  // LOSS_WEIGHT = 1.0
}

extern "C" void kernel_launch(void* const* d_in, const int* in_sizes, int n_in,
                              void* d_out, int out_size, void* d_ws, size_t ws_size,
                              hipStream_t stream) {
  const float* x = (const float*)d_in[0];
  float* out = (float*)d_out;
  char* ws = (char*)d_ws;

  float* sim = (float*)ws;                                  // 64 MB
  float* rinv = (float*)(ws + (size_t)NN * 4);              // 16 KB
  Meta* meta = (Meta*)(ws + (size_t)NN * 4 + 16384);        // small, 8-aligned

  // thresholds' ranks: identical IEEE-double arithmetic to the Python ref
  const unsigned int kneg = (unsigned int)ceil((double)NN * 0.2);          // 3355444
  const unsigned int kpos = (unsigned int)ceil((double)NN * (1.0 - 0.2));  // 13421773

  hipMemsetAsync(meta, 0, sizeof(Meta), stream);
  init_meta<<<1, 1, 0, stream>>>(meta, kneg, kpos);

  row_norms<<<N, 256, 0, stream>>>(x, rinv);

  dim3 ggrid(N / BM, N / BN);
  gemm_sim<<<ggrid, 256, 0, stream>>>(x, rinv, sim);

  for (int pass = 0; pass < 4; ++pass) {
    const unsigned int shift = 24u - 8u * pass;
    const unsigned int mask = (pass == 0) ? 0u : (0xFFFFFFFFu << (shift + 8));
    const int dup = (pass == 0) ? 1 : 0;
    hist_pass<<<2048, 256, 0, stream>>>(sim, meta, shift, mask, dup);
    scan_pass<<<1, 64, 0, stream>>>(meta, shift, dup);
  }

  loss_pass<<<2048, 256, 0, stream>>>(sim, meta);
  finalize<<<1, 1, 0, stream>>>(meta, out);
}